// Round 3
// baseline (11059.306 us; speedup 1.0000x reference)
//
#include <hip/hip_runtime.h>
#include <math.h>

constexpr int kB  = 256;
constexpr int kT  = 512;
constexpr int kM  = 3;
constexpr int kD  = 256;
constexpr int kNS = 64;
constexpr int kH  = 128;

__device__ __forceinline__ float sigmoidf_(float v) { return 1.0f / (1.0f + __expf(-v)); }
__device__ __forceinline__ float dot4(float4 a, float4 b) {
    return a.x*b.x + a.y*b.y + a.z*b.z + a.w*b.w;
}

// One-time: transpose Whh[128][384] -> WhhT[384][128] in d_ws (re-run every
// launch since d_ws is re-poisoned before every timed call).
extern "C" __global__ void __launch_bounds__(256)
whh_transpose(const float* __restrict__ Whh, float* __restrict__ WhhT) {
    const int o = blockIdx.x * 256 + threadIdx.x;   // 0..49151
    const int j = o >> 7, k = o & 127;
    WhhT[o] = Whh[k * 384 + j];
}

// One block per batch row; 256 threads; T-loop inside.
// S and A register-cached per thread (fp32); Whh streamed from L2 via WhhT,
// overlapped (waves 2-3) with the serial gate tail (wave 0).
extern "C" __global__ void __launch_bounds__(256)
disc_kernel(const float* __restrict__ x,   const float* __restrict__ y,
            const float* __restrict__ U,   const float* __restrict__ S,
            const float* __restrict__ A,   const float* __restrict__ Wih,
            const float* __restrict__ bih, const float* __restrict__ bhh,
            const float* __restrict__ Wd,  const float* __restrict__ bd,
            const float* __restrict__ WhhT,
            float* __restrict__ out_o,  float* __restrict__ out_p)
{
    const int b    = blockIdx.x;
    const int tid  = threadIdx.x;
    const int lane = tid & 63;
    const int wid  = tid >> 6;

    __shared__ __align__(16) float sh_K[kM * kD];      // 768
    __shared__ __align__(16) float sh_part[12 * 64];   // 768
    __shared__ __align__(16) float sh_ns[kM * kNS];    // 192
    __shared__ __align__(16) float sh_pre[256];        // r,z preacts (gi+gh)
    __shared__ __align__(16) float sh_gin[128];        // n-part gi only
    __shared__ __align__(16) float sh_gh[384];
    __shared__ __align__(16) float sh_h[kH];
    __shared__ __align__(16) float sh_s[kNS];
    __shared__ __align__(16) float sh_Wih[4 * 384];
    __shared__ __align__(16) float sh_bih[384];
    __shared__ __align__(16) float sh_bhh[384];
    __shared__ float sh_Wd[384];
    __shared__ float sh_bd[3];
    __shared__ float sh_encp[12];                      // per-wave K max partials [m*4+wid]
    __shared__ float sh_gate[3];
    __shared__ __align__(16) float sh_xt[4];
    __shared__ float sh_x2, sh_s2, sh_err;
    __shared__ float sh_yt[2];                         // DOUBLE-BUFFERED (R2 race fix)

    // ---- Persistent register caches --------------------------------------
    // S rows + U row for (m, d=tid):  3*16 float4 + 3 float4 = 204 regs
    const float4* S4 = reinterpret_cast<const float4*>(S);
    float4 S_reg[3][16];
    float4 U_row[3];
    float  Cc[3];
#pragma unroll
    for (int p = 0; p < 3; ++p) {
        const int row = p * kD + tid;
        U_row[p] = reinterpret_cast<const float4*>(U)[row];
        float s2sum = 0.f;
#pragma unroll
        for (int j = 0; j < 16; ++j) {
            S_reg[p][j] = S4[row * 16 + j];
            s2sum += dot4(S_reg[p][j], S_reg[p][j]);
        }
        Cc[p] = -0.5f * (dot4(U_row[p], U_row[p]) + s2sum);
    }
    // A slice for Phase B mapping (wid,e)->(m,c), lane = n: 192 regs
    float A_reg[3][64];
#pragma unroll
    for (int e = 0; e < 3; ++e) {
        const int q = wid * 3 + e, m = q >> 2, c = q & 3;
        const float* Ab = A + (m * kD + c * 64) * kNS + lane;
#pragma unroll 16
        for (int dd = 0; dd < 64; ++dd)
            A_reg[e][dd] = Ab[dd * kNS];
    }

    // ---- LDS preload of small weights ------------------------------------
    for (int i = tid; i < 1536; i += 256) sh_Wih[i] = Wih[i];
    for (int i = tid; i < 384; i += 256) {
        sh_bih[i] = bih[i];
        sh_bhh[i] = bhh[i];
        sh_gh[i]  = bhh[i];          // gh for t=0 (h=0) = bhh
    }
    for (int i = tid; i < 381; i += 256) sh_Wd[i] = Wd[i];
    if (tid < 3) { sh_bd[tid] = bd[tid]; sh_gate[tid] = (tid == 2) ? 0.3334f : 0.3333f; }
    if (tid < kNS) sh_s[tid] = 0.f;
    if (tid < kH)  sh_h[tid] = 0.f;
    if (tid == 0) {
        sh_err = 1.0f; sh_s2 = 0.f;
        float4 xv = reinterpret_cast<const float4*>(x)[(size_t)b * kT];
        reinterpret_cast<float4*>(sh_xt)[0] = xv;
        sh_x2 = dot4(xv, xv);
        sh_yt[0] = y[(size_t)b * kT];
    }
    __syncthreads();

    for (int t = 0; t < kT; ++t) {
        // ===== PA: K[m,tid] from registers + wave-level encoded partials ====
        {
            const float scal = -0.5f * (sh_x2 + sh_s2);
            const float4 xt4 = reinterpret_cast<const float4*>(sh_xt)[0];
            const float4* s4 = reinterpret_cast<const float4*>(sh_s);
            float dot[3] = {0.f, 0.f, 0.f};
#pragma unroll
            for (int j = 0; j < 16; ++j) {
                float4 sv = s4[j];                       // LDS broadcast
                dot[0] += dot4(sv, S_reg[0][j]);
                dot[1] += dot4(sv, S_reg[1][j]);
                dot[2] += dot4(sv, S_reg[2][j]);
            }
            float kk[3];
#pragma unroll
            for (int p = 0; p < 3; ++p) {
                kk[p] = __expf(scal + Cc[p] + dot4(xt4, U_row[p]) + dot[p]);
                sh_K[p * kD + tid] = kk[p];
            }
            float m0 = kk[0], m1 = kk[1], m2 = kk[2];
#pragma unroll
            for (int o = 32; o > 0; o >>= 1) {
                m0 = fmaxf(m0, __shfl_xor(m0, o, 64));
                m1 = fmaxf(m1, __shfl_xor(m1, o, 64));
                m2 = fmaxf(m2, __shfl_xor(m2, o, 64));
            }
            if (lane == 0) {
                sh_encp[0 * 4 + wid] = m0;
                sh_encp[1 * 4 + wid] = m1;
                sh_encp[2 * 4 + wid] = m2;
            }
        }
        __syncthreads();                                  // (1)

        // ===== PB: new_state partials, pure FMA from A_reg =================
        {
            const float4* K4 = reinterpret_cast<const float4*>(sh_K);
#pragma unroll
            for (int e = 0; e < 3; ++e) {
                const int q = wid * 3 + e, m = q >> 2, c = q & 3;
                const float4* Kb = K4 + m * 64 + c * 16;
                float acc = 0.f;
#pragma unroll
                for (int j = 0; j < 16; ++j) {
                    float4 kv = Kb[j];                   // LDS broadcast
                    acc += kv.x * A_reg[e][4*j]   + kv.y * A_reg[e][4*j+1]
                         + kv.z * A_reg[e][4*j+2] + kv.w * A_reg[e][4*j+3];
                }
                sh_part[q * 64 + lane] = acc;
            }
        }
        __syncthreads();                                  // (2)

        // ===== PC: ns reduce + gi / preact =================================
        if (tid < 192) {
            const int m = tid >> 6, n = tid & 63;
            sh_ns[m * 64 + n] = sh_part[(4*m+0)*64 + n] + sh_part[(4*m+1)*64 + n]
                              + sh_part[(4*m+2)*64 + n] + sh_part[(4*m+3)*64 + n];
        }
        {
            const float e0 = fmaxf(fmaxf(sh_encp[0], sh_encp[1]), fmaxf(sh_encp[2],  sh_encp[3]));
            const float e1 = fmaxf(fmaxf(sh_encp[4], sh_encp[5]), fmaxf(sh_encp[6],  sh_encp[7]));
            const float e2 = fmaxf(fmaxf(sh_encp[8], sh_encp[9]), fmaxf(sh_encp[10], sh_encp[11]));
            const float er = sh_err;
            const int j = tid;
            float gi = sh_bih[j] + e0 * sh_Wih[j]       + e1 * sh_Wih[384 + j]
                                 + e2 * sh_Wih[768 + j] + er * sh_Wih[1152 + j];
            sh_pre[j] = gi + sh_gh[j];                   // r (j<128) and z (128..255)
            if (tid < 128) {
                const int j2 = 256 + tid;
                sh_gin[tid] = sh_bih[j2] + e0 * sh_Wih[j2]       + e1 * sh_Wih[384 + j2]
                                         + e2 * sh_Wih[768 + j2] + er * sh_Wih[1152 + j2];
            }
        }
        __syncthreads();                                  // (3)

        // ===== PD: GRU elementwise (in-place h update) =====================
        if (tid < kH) {
            const float r  = sigmoidf_(sh_pre[tid]);
            const float z  = sigmoidf_(sh_pre[128 + tid]);
            const float nn = tanhf(sh_gin[tid] + r * sh_gh[256 + tid]);
            sh_h[tid] = (1.f - z) * nn + z * sh_h[tid];
        }
        __syncthreads();                                  // (4)

        // ===== PE: wave0 = serial tail; wave1 = x/y prefetch (next slot);
        //           waves2-3 = gh for t+1 (Whh stream, the long pole) ========
        if (wid == 0) {
            const float h1 = sh_h[lane];
            const float h2 = (lane < 63) ? sh_h[64 + lane] : 0.f;
            const float w00 = sh_Wd[lane*3+0], w01 = sh_Wd[lane*3+1], w02 = sh_Wd[lane*3+2];
            float w10 = 0.f, w11 = 0.f, w12 = 0.f;
            if (lane < 63) { w10 = sh_Wd[(64+lane)*3+0]; w11 = sh_Wd[(64+lane)*3+1]; w12 = sh_Wd[(64+lane)*3+2]; }
            float a0 = h1*w00 + h2*w10;
            float a1 = h1*w01 + h2*w11;
            float a2 = h1*w02 + h2*w12;
#pragma unroll
            for (int o = 32; o > 0; o >>= 1) {
                a0 += __shfl_xor(a0, o, 64);
                a1 += __shfl_xor(a1, o, 64);
                a2 += __shfl_xor(a2, o, 64);
            }
            const float l0 = a0 + sh_bd[0], l1 = a1 + sh_bd[1], l2 = a2 + sh_bd[2];
            const float mx = fmaxf(l0, fmaxf(l1, l2));
            const float x0 = __expf(l0 - mx), x1 = __expf(l1 - mx), x2 = __expf(l2 - mx);
            const float inv = 1.f / (x0 + x1 + x2);
            const float theta = sigmoidf_(sh_h[127]);
            const float omt = 1.f - theta;
            const float gp0 = sh_gate[0], gp1 = sh_gate[1], gp2 = sh_gate[2];
            const float g0 = x0*inv*theta + gp0*omt;
            const float g1 = x1*inv*theta + gp1*omt;
            const float g2 = x2*inv*theta + gp2*omt;
            if (lane == 0) {
                sh_gate[0] = g0; sh_gate[1] = g1; sh_gate[2] = g2;
                out_p[(size_t)b * kT + t] = g0*(1.f-g0) + g1*(1.f-g1) + g2*(1.f-g2);
            }
            const float sn = g0*sh_ns[lane] + g1*sh_ns[64 + lane] + g2*sh_ns[128 + lane];
            sh_s[lane] = sn;
            if (lane == 63) {
                out_o[(size_t)b * kT + t] = sn;
                sh_err = sn - sh_yt[t & 1];              // reads CURRENT slot — no race
            }
            float ss = sn * sn;
#pragma unroll
            for (int o = 32; o > 0; o >>= 1) ss += __shfl_xor(ss, o, 64);
            if (lane == 0) sh_s2 = ss;
        } else if (wid == 1) {
            if (lane == 0 && (t + 1) < kT) {
                float4 xv = reinterpret_cast<const float4*>(x)[(size_t)b * kT + t + 1];
                reinterpret_cast<float4*>(sh_xt)[0] = xv;
                sh_x2 = dot4(xv, xv);
                sh_yt[(t + 1) & 1] = y[(size_t)b * kT + t + 1];   // writes NEXT slot
            }
        } else {
            // gh_{t+1} = bhh + WhhT @ h_{t+1}; 128 threads x 3 rows each
            const int q = tid - 128;                      // 0..127
            const float4* W0 = reinterpret_cast<const float4*>(WhhT) + (q      ) * 32;
            const float4* W1 = reinterpret_cast<const float4*>(WhhT) + (q + 128) * 32;
            const float4* W2 = reinterpret_cast<const float4*>(WhhT) + (q + 256) * 32;
            const float4* h4 = reinterpret_cast<const float4*>(sh_h);
            float acc0 = sh_bhh[q], acc1 = sh_bhh[q + 128], acc2 = sh_bhh[q + 256];
#pragma unroll 8
            for (int k4 = 0; k4 < 32; ++k4) {
                const float4 hv = h4[k4];                // LDS broadcast
                acc0 += dot4(hv, W0[k4]);
                acc1 += dot4(hv, W1[k4]);
                acc2 += dot4(hv, W2[k4]);
            }
            sh_gh[q] = acc0; sh_gh[q + 128] = acc1; sh_gh[q + 256] = acc2;
        }
        __syncthreads();                                  // (5)
    }
}

extern "C" void kernel_launch(void* const* d_in, const int* in_sizes, int n_in,
                              void* d_out, int out_size, void* d_ws, size_t ws_size,
                              hipStream_t stream)
{
    const float* x   = (const float*)d_in[0];
    const float* y   = (const float*)d_in[1];
    const float* U   = (const float*)d_in[2];
    const float* S   = (const float*)d_in[3];
    const float* A   = (const float*)d_in[4];
    const float* Wih = (const float*)d_in[5];
    const float* Whh = (const float*)d_in[6];
    const float* bih = (const float*)d_in[7];
    const float* bhh = (const float*)d_in[8];
    const float* Wd  = (const float*)d_in[9];
    const float* bd  = (const float*)d_in[10];

    float* WhhT  = (float*)d_ws;                 // 49152 floats = 196 KB scratch
    float* out_o = (float*)d_out;                // (B, T) preds
    float* out_p = out_o + kB * kT;              // (B, T, 1) penalties

    hipLaunchKernelGGL(whh_transpose, dim3(192), dim3(256), 0, stream, Whh, WhhT);
    hipLaunchKernelGGL(disc_kernel, dim3(kB), dim3(256), 0, stream,
                       x, y, U, S, A, Wih, bih, bhh, Wd, bd, WhhT, out_o, out_p);
}

// Round 4
// 4698.151 us; speedup vs baseline: 2.3540x; 2.3540x over previous
//
#include <hip/hip_runtime.h>
#include <math.h>

constexpr int kB  = 256;
constexpr int kT  = 512;
constexpr int kM  = 3;
constexpr int kD  = 256;
constexpr int kNS = 64;
constexpr int kH  = 128;

__device__ __forceinline__ float sigmoidf_(float v) { return 1.0f / (1.0f + __expf(-v)); }
__device__ __forceinline__ float dot4(float4 a, float4 b) {
    return a.x*b.x + a.y*b.y + a.z*b.z + a.w*b.w;
}

// One-time: transpose Whh[128][384] -> WhhT[384][128] in d_ws.
extern "C" __global__ void __launch_bounds__(256)
whh_transpose(const float* __restrict__ Whh, float* __restrict__ WhhT) {
    const int o = blockIdx.x * 256 + threadIdx.x;   // 0..49151
    const int j = o >> 7, k = o & 127;
    WhhT[o] = Whh[k * 384 + j];
}

// One block (512 threads) per batch row. S+A register-cached at exactly
// 192 floats/thread (uniform across all threads => no footprint union).
// Whh streamed from L2 in two chunks overlapped with tail (PE) and einsum (PB).
extern "C" __global__ void __launch_bounds__(512, 2)
disc_kernel(const float* __restrict__ x,   const float* __restrict__ y,
            const float* __restrict__ U,   const float* __restrict__ S,
            const float* __restrict__ A,   const float* __restrict__ Wih,
            const float* __restrict__ bih, const float* __restrict__ bhh,
            const float* __restrict__ Wd,  const float* __restrict__ bd,
            const float* __restrict__ WhhT,
            float* __restrict__ out_o,  float* __restrict__ out_p)
{
    const int b    = blockIdx.x;
    const int tid  = threadIdx.x;
    const int lane = tid & 63;
    const int wid  = tid >> 6;
    const int hb   = tid & 1;                 // half index for the shared m=2 row

    __shared__ __align__(16) float sh_K[768];
    __shared__ __align__(16) float sh_part[512];
    __shared__ __align__(16) float sh_part2[512];
    __shared__ __align__(16) float sh_ns[192];
    __shared__ __align__(16) float sh_pre[256];
    __shared__ __align__(16) float sh_gin[128];
    __shared__ __align__(16) float sh_gh[384];
    __shared__ __align__(16) float sh_h[kH];
    __shared__ __align__(16) float sh_s[kNS];
    __shared__ __align__(16) float sh_Wih[4 * 384];
    __shared__ __align__(16) float sh_bih[384];
    __shared__ __align__(16) float sh_bhh[384];
    __shared__ float sh_Wd[384];
    __shared__ float sh_bd[4];
    __shared__ float sh_encpA[8];             // wave maxes: slots 0-3 = m0, 4-7 = m1
    __shared__ float sh_encpB[8];             // wave maxes for m2
    __shared__ float sh_gate[4];
    __shared__ __align__(16) float sh_xt[4];
    __shared__ float sh_x2, sh_s2, sh_err;
    __shared__ float sh_yt[2];

    // ---- Persistent register caches: 64+32 S, 64+32 A, U, C = 200 floats ---
    const float4* S4 = reinterpret_cast<const float4*>(S);
    const float4* U4 = reinterpret_cast<const float4*>(U);

    float4 Sa[16]; float4 Ua; float Ca;       // full row: K-pair = tid (m=tid>>8)
    float4 Sb[8];  float Ub0, Ub1; float Cb;  // half row: K-pair = 512+(tid>>1)
    {
        float ss = 0.f;
#pragma unroll
        for (int j = 0; j < 16; ++j) { Sa[j] = S4[tid * 16 + j]; ss += dot4(Sa[j], Sa[j]); }
        Ua = U4[tid];
        Ca = -0.5f * (dot4(Ua, Ua) + ss);
    }
    const int pb = 512 + (tid >> 1);
    {
        float ss = 0.f;
#pragma unroll
        for (int j = 0; j < 8; ++j) { Sb[j] = S4[pb * 16 + hb * 8 + j]; ss += dot4(Sb[j], Sb[j]); }
        Ub0 = U[pb * 4 + hb * 2 + 0];
        Ub1 = U[pb * 4 + hb * 2 + 1];
        Cb = -0.5f * (Ub0*Ub0 + Ub1*Ub1 + ss);
    }
    // A task a: chunk task tau = tid: pair pa = tid>>2 in [0,128), chunk ca
    const int pa = tid >> 2, ca = tid & 3, ma = pa >> 6, na = pa & 63;
    float A1[64];
#pragma unroll
    for (int dd = 0; dd < 64; ++dd)
        A1[dd] = A[(ma * 256 + ca * 64 + dd) * 64 + na];
    // A task b: m=2 chunk halves: cb2 = tid>>1 in [0,256)
    const int cb2 = tid >> 1, cbc = cb2 & 3, nb = cb2 >> 2;
    float A2[32];
#pragma unroll
    for (int dd = 0; dd < 32; ++dd)
        A2[dd] = A[(512 + cbc * 64 + hb * 32 + dd) * 64 + nb];

    // ---- LDS preload -----------------------------------------------------
    for (int i = tid; i < 1536; i += 512) sh_Wih[i] = Wih[i];
    for (int i = tid; i < 384; i += 512) {
        sh_bih[i] = bih[i];
        sh_bhh[i] = bhh[i];
        sh_gh[i]  = bhh[i];                   // gh(t=0) with h=0
    }
    for (int i = tid; i < 381; i += 512) sh_Wd[i] = Wd[i];
    if (tid < 3) { sh_bd[tid] = bd[tid]; sh_gate[tid] = (tid == 2) ? 0.3334f : 0.3333f; }
    if (tid < kNS) sh_s[tid] = 0.f;
    if (tid < kH)  sh_h[tid] = 0.f;
    if (tid == 0) {
        sh_err = 1.0f; sh_s2 = 0.f;
        float4 xv = reinterpret_cast<const float4*>(x)[(size_t)b * kT];
        reinterpret_cast<float4*>(sh_xt)[0] = xv;
        sh_x2 = dot4(xv, xv);
        sh_yt[0] = y[(size_t)b * kT];
    }
    __syncthreads();

    for (int t = 0; t < kT; ++t) {
        // ===== PA: K for pair tid (full) + pair 512+(tid>>1) (half+shuffle) =
        {
            const float scal = -0.5f * (sh_x2 + sh_s2);
            const float4 xt4 = reinterpret_cast<const float4*>(sh_xt)[0];
            const float4* s4 = reinterpret_cast<const float4*>(sh_s);
            float da = 0.f, db = 0.f;
#pragma unroll
            for (int j = 0; j < 16; ++j) da += dot4(s4[j], Sa[j]);
#pragma unroll
            for (int j = 0; j < 8; ++j)  db += dot4(s4[hb * 8 + j], Sb[j]);
            const float kk_a = __expf(scal + Ca + dot4(xt4, Ua) + da);
            const float xbp  = hb ? (xt4.z*Ub0 + xt4.w*Ub1) : (xt4.x*Ub0 + xt4.y*Ub1);
            const float ph   = db + Cb + xbp;
            const float po   = __shfl_xor(ph, 1, 64);
            const float kk_b = __expf(scal + ph + po);
            sh_K[tid] = kk_a;
            if (hb == 0) sh_K[512 + (tid >> 1)] = kk_b;
            float mA = kk_a, mB = kk_b;
#pragma unroll
            for (int o = 32; o > 0; o >>= 1) {
                mA = fmaxf(mA, __shfl_xor(mA, o, 64));
                mB = fmaxf(mB, __shfl_xor(mB, o, 64));
            }
            if (lane == 0) { sh_encpA[wid] = mA; sh_encpB[wid] = mB; }
        }
        __syncthreads();                                  // (1)

        // ===== PB: einsum partials (+ gh chunk2 on waves 5-7) ===============
        {
            const float4* K4 = reinterpret_cast<const float4*>(sh_K + ma * 256 + ca * 64);
            float acc = 0.f;
#pragma unroll
            for (int j = 0; j < 16; ++j) {
                const float4 kv = K4[j];
                acc += kv.x*A1[4*j] + kv.y*A1[4*j+1] + kv.z*A1[4*j+2] + kv.w*A1[4*j+3];
            }
            sh_part[tid] = acc;
            const float4* K4b = reinterpret_cast<const float4*>(sh_K + 512 + cbc * 64 + hb * 32);
            float accb = 0.f;
#pragma unroll
            for (int j = 0; j < 8; ++j) {
                const float4 kv = K4b[j];
                accb += kv.x*A2[4*j] + kv.y*A2[4*j+1] + kv.z*A2[4*j+2] + kv.w*A2[4*j+3];
            }
            sh_part2[tid] = accb;
            if (tid >= 320) {                              // gh rows 192..383 (uses h_t)
                const int row = tid - 128;
                const float4* W4 = reinterpret_cast<const float4*>(WhhT + row * 128);
                const float4* h4 = reinterpret_cast<const float4*>(sh_h);
                float g = sh_bhh[row];
#pragma unroll 8
                for (int k4 = 0; k4 < 32; ++k4) g += dot4(h4[k4], W4[k4]);
                sh_gh[row] = g;
            }
        }
        __syncthreads();                                  // (2)

        // ===== PC: ns reduce + gi combine ==================================
        if (tid < 192) {
            float v;
            if (tid < 128) {
                const float4 p = reinterpret_cast<const float4*>(sh_part)[tid];
                v = (p.x + p.y) + (p.z + p.w);
            } else {
                const int q = tid - 128;
                const float4 p0 = reinterpret_cast<const float4*>(sh_part2)[2*q];
                const float4 p1 = reinterpret_cast<const float4*>(sh_part2)[2*q+1];
                v = ((p0.x + p0.y) + (p0.z + p0.w)) + ((p1.x + p1.y) + (p1.z + p1.w));
            }
            sh_ns[tid] = v;
        }
        if (tid >= 128) {
            const int j = tid - 128;                       // 0..383
            const float e0 = fmaxf(fmaxf(sh_encpA[0], sh_encpA[1]), fmaxf(sh_encpA[2], sh_encpA[3]));
            const float e1 = fmaxf(fmaxf(sh_encpA[4], sh_encpA[5]), fmaxf(sh_encpA[6], sh_encpA[7]));
            const float e2 = fmaxf(fmaxf(fmaxf(sh_encpB[0], sh_encpB[1]), fmaxf(sh_encpB[2], sh_encpB[3])),
                                   fmaxf(fmaxf(sh_encpB[4], sh_encpB[5]), fmaxf(sh_encpB[6], sh_encpB[7])));
            const float er = sh_err;
            const float gi = sh_bih[j] + e0 * sh_Wih[j]       + e1 * sh_Wih[384 + j]
                                       + e2 * sh_Wih[768 + j] + er * sh_Wih[1152 + j];
            if (j < 256) sh_pre[j] = gi + sh_gh[j];
            else         sh_gin[j - 256] = gi;
        }
        __syncthreads();                                  // (3)

        // ===== PD: GRU elementwise =========================================
        if (tid < kH) {
            const float r  = sigmoidf_(sh_pre[tid]);
            const float z  = sigmoidf_(sh_pre[128 + tid]);
            const float nn = tanhf(sh_gin[tid] + r * sh_gh[256 + tid]);
            sh_h[tid] = (1.f - z) * nn + z * sh_h[tid];
        }
        __syncthreads();                                  // (4)

        // ===== PE: wave0 tail | wave1 prefetch | waves2-4 gh chunk1 ========
        if (wid == 0) {
            const float h1 = sh_h[lane];
            const float h2 = (lane < 63) ? sh_h[64 + lane] : 0.f;
            const float w00 = sh_Wd[lane*3+0], w01 = sh_Wd[lane*3+1], w02 = sh_Wd[lane*3+2];
            float w10 = 0.f, w11 = 0.f, w12 = 0.f;
            if (lane < 63) { w10 = sh_Wd[(64+lane)*3+0]; w11 = sh_Wd[(64+lane)*3+1]; w12 = sh_Wd[(64+lane)*3+2]; }
            float a0 = h1*w00 + h2*w10;
            float a1 = h1*w01 + h2*w11;
            float a2 = h1*w02 + h2*w12;
#pragma unroll
            for (int o = 32; o > 0; o >>= 1) {
                a0 += __shfl_xor(a0, o, 64);
                a1 += __shfl_xor(a1, o, 64);
                a2 += __shfl_xor(a2, o, 64);
            }
            const float l0 = a0 + sh_bd[0], l1 = a1 + sh_bd[1], l2 = a2 + sh_bd[2];
            const float mx = fmaxf(l0, fmaxf(l1, l2));
            const float x0 = __expf(l0 - mx), x1 = __expf(l1 - mx), x2 = __expf(l2 - mx);
            const float inv = 1.f / (x0 + x1 + x2);
            const float theta = sigmoidf_(sh_h[127]);
            const float omt = 1.f - theta;
            const float g0 = x0*inv*theta + sh_gate[0]*omt;
            const float g1 = x1*inv*theta + sh_gate[1]*omt;
            const float g2 = x2*inv*theta + sh_gate[2]*omt;
            if (lane == 0) {
                sh_gate[0] = g0; sh_gate[1] = g1; sh_gate[2] = g2;
                out_p[(size_t)b * kT + t] = g0*(1.f-g0) + g1*(1.f-g1) + g2*(1.f-g2);
            }
            const float sn = g0*sh_ns[lane] + g1*sh_ns[64 + lane] + g2*sh_ns[128 + lane];
            sh_s[lane] = sn;
            if (lane == 63) {
                out_o[(size_t)b * kT + t] = sn;
                sh_err = sn - sh_yt[t & 1];
            }
            float ss = sn * sn;
#pragma unroll
            for (int o = 32; o > 0; o >>= 1) ss += __shfl_xor(ss, o, 64);
            if (lane == 0) sh_s2 = ss;
        } else if (wid == 1) {
            if (lane == 0 && (t + 1) < kT) {
                float4 xv = reinterpret_cast<const float4*>(x)[(size_t)b * kT + t + 1];
                reinterpret_cast<float4*>(sh_xt)[0] = xv;
                sh_x2 = dot4(xv, xv);
                sh_yt[(t + 1) & 1] = y[(size_t)b * kT + t + 1];
            }
        } else if (tid < 320) {                            // gh rows 0..191 (uses h_{t+1})
            const int row = tid - 128;
            const float4* W4 = reinterpret_cast<const float4*>(WhhT + row * 128);
            const float4* h4 = reinterpret_cast<const float4*>(sh_h);
            float g = sh_bhh[row];
#pragma unroll 8
            for (int k4 = 0; k4 < 32; ++k4) g += dot4(h4[k4], W4[k4]);
            sh_gh[row] = g;
        }
        __syncthreads();                                  // (5)
    }
}

extern "C" void kernel_launch(void* const* d_in, const int* in_sizes, int n_in,
                              void* d_out, int out_size, void* d_ws, size_t ws_size,
                              hipStream_t stream)
{
    const float* x   = (const float*)d_in[0];
    const float* y   = (const float*)d_in[1];
    const float* U   = (const float*)d_in[2];
    const float* S   = (const float*)d_in[3];
    const float* A   = (const float*)d_in[4];
    const float* Wih = (const float*)d_in[5];
    const float* Whh = (const float*)d_in[6];
    const float* bih = (const float*)d_in[7];
    const float* bhh = (const float*)d_in[8];
    const float* Wd  = (const float*)d_in[9];
    const float* bd  = (const float*)d_in[10];

    float* WhhT  = (float*)d_ws;                 // 49152 floats = 192 KB scratch
    float* out_o = (float*)d_out;                // (B, T) preds
    float* out_p = out_o + kB * kT;              // (B, T, 1) penalties

    hipLaunchKernelGGL(whh_transpose, dim3(192), dim3(256), 0, stream, Whh, WhhT);
    hipLaunchKernelGGL(disc_kernel, dim3(kB), dim3(512), 0, stream,
                       x, y, U, S, A, Wih, bih, bhh, Wd, bd, WhhT, out_o, out_p);
}